// Round 1
// baseline (70.614 us; speedup 1.0000x reference)
//
#include <hip/hip_runtime.h>
#include <math.h>

#define HH 2048
#define WW 2048

// Gaussian sigma=2, 5 taps, normalized (computed in double, rounded to float)
#define GW0 0.15246914402033867f
#define GW1 0.22184129554377693f
#define GW2 0.25137912086578894f

__global__ __launch_bounds__(256) void steal_main(const float* __restrict__ pred,
                                                  const float* __restrict__ lab,
                                                  float* __restrict__ acc,
                                                  int use_partials) {
    __shared__ float s_lab[24][25];   // label halo, coord = ty0-4+r (reflected value stored)
    __shared__ float s_h[24][21];     // horizontal gaussian pass, 24 rows x 20 out-cols
    __shared__ float s_blur[20][21];  // blur(clamp(coord)), coords ty0-2 .. ty0+17
    __shared__ float s_gx[18][19];    // gx(clamp(coord)), coords ty0-1 .. ty0+16
    __shared__ float s_gy[18][19];
    __shared__ float s_red[4];

    const int tx = threadIdx.x, ty = threadIdx.y;
    const int tid = ty * 16 + tx;
    const int tx0 = blockIdx.x * 16, ty0 = blockIdx.y * 16;

    // ---- load labels with reflect padding of the full image ----
    for (int i = tid; i < 24 * 24; i += 256) {
        int r = i / 24, c = i % 24;
        int gy_ = ty0 - 4 + r;
        int gx_ = tx0 - 4 + c;
        gy_ = (gy_ < 0) ? -gy_ : ((gy_ >= HH) ? 2 * HH - 2 - gy_ : gy_);
        gx_ = (gx_ < 0) ? -gx_ : ((gx_ >= WW) ? 2 * WW - 2 - gx_ : gx_);
        s_lab[r][c] = lab[gy_ * WW + gx_];
    }
    __syncthreads();

    // ---- horizontal gaussian: 24 rows x 20 output cols ----
    for (int i = tid; i < 24 * 20; i += 256) {
        int r = i / 20, j = i % 20;
        int qx = tx0 - 2 + j;
        qx = min(max(qx, 0), WW - 1);          // clamp output coordinate
        int b = qx - (tx0 - 4);                // slot of coord qx
        s_h[r][j] = GW0 * (s_lab[r][b - 2] + s_lab[r][b + 2]) +
                    GW1 * (s_lab[r][b - 1] + s_lab[r][b + 1]) +
                    GW2 * s_lab[r][b];
    }
    __syncthreads();

    // ---- vertical gaussian: 20 x 20, slot holds blur(clamp(coord)) ----
    for (int i = tid; i < 20 * 20; i += 256) {
        int r = i / 20, j = i % 20;
        int qy = ty0 - 2 + r;
        qy = min(max(qy, 0), HH - 1);
        int b = qy - (ty0 - 4);
        s_blur[r][j] = GW0 * (s_h[b - 2][j] + s_h[b + 2][j]) +
                       GW1 * (s_h[b - 1][j] + s_h[b + 1][j]) +
                       GW2 * s_h[b][j];
    }
    __syncthreads();

    // ---- sobel gx, gy on blur (replicate pad): 18 x 18 ----
    for (int i = tid; i < 18 * 18; i += 256) {
        int r = i / 18, j = i % 18;
        int qy = ty0 - 1 + r;  qy = min(max(qy, 0), HH - 1);  // clamp own coord first
        int qx = tx0 - 1 + j;  qx = min(max(qx, 0), WW - 1);
        int br = qy - (ty0 - 2), bc = qx - (tx0 - 2);
        float m11 = s_blur[br - 1][bc - 1], m12 = s_blur[br - 1][bc], m13 = s_blur[br - 1][bc + 1];
        float m21 = s_blur[br][bc - 1],                              m23 = s_blur[br][bc + 1];
        float m31 = s_blur[br + 1][bc - 1], m32 = s_blur[br + 1][bc], m33 = s_blur[br + 1][bc + 1];
        s_gx[r][j] = ((m13 - m11) + 2.0f * (m23 - m21) + (m33 - m31)) * 0.125f;
        s_gy[r][j] = ((m31 - m11) + 2.0f * (m32 - m12) + (m33 - m13)) * 0.125f;
    }
    __syncthreads();

    // ---- per pixel: second sobel, angle, section, directional loss ----
    const int py = ty0 + ty, px = tx0 + tx;
    const int gr = ty + 1, gc = tx + 1;  // slot of coord (py, px) in 18x18 tiles

    float a11 = s_gx[gr - 1][gc - 1], a12 = s_gx[gr - 1][gc], a13 = s_gx[gr - 1][gc + 1];
    float a21 = s_gx[gr][gc - 1],                            a23 = s_gx[gr][gc + 1];
    float a31 = s_gx[gr + 1][gc - 1], a32 = s_gx[gr + 1][gc], a33 = s_gx[gr + 1][gc + 1];
    float b11 = s_gy[gr - 1][gc - 1], b12 = s_gy[gr - 1][gc], b13 = s_gy[gr - 1][gc + 1];
    float b21 = s_gy[gr][gc - 1],                            b23 = s_gy[gr][gc + 1];
    float b31 = s_gy[gr + 1][gc - 1], b32 = s_gy[gr + 1][gc], b33 = s_gy[gr + 1][gc + 1];

    float gxx = ((a13 - a11) + 2.0f * (a23 - a21) + (a33 - a31)) * 0.125f;
    float gxy = ((b13 - b11) + 2.0f * (b23 - b21) + (b33 - b31)) * 0.125f;  // sobel_x on gy
    float gyy = ((b31 - b11) + 2.0f * (b32 - b12) + (b33 - b13)) * 0.125f;  // sobel_y on gy
    (void)a12; (void)a32;

    float sg = -(gxy + 1e-6f);
    float sgn = (sg > 0.0f) ? 1.0f : ((sg < 0.0f) ? -1.0f : 0.0f);
    float ratio = gyy * sgn / (gxx + 1e-6f);
    float a = atanf(ratio);

    const float PI8  = 0.39269908169872414f;
    const float PI38 = 1.1780972450961724f;
    const float PIH  = 1.5707963267948966f;

    int sy = 0, sx = 0;
    bool has = false;
    if (a >= -PI8 && a < PI8)            { sy = 0; sx = 1;  has = true; }  // horiz
    else if (a >= PI38 && a < PIH)       { sy = 1; sx = 0;  has = true; }  // vert (+)
    else if (a >= -PIH && a < -PI38)     { sy = 1; sx = 0;  has = true; }  // vert (-)
    else if (a >= PI8 && a < PI38)       { sy = 1; sx = 1;  has = true; }  // lead diag
    else if (a >= -PI38 && a < -PI8)     { sy = 1; sx = -1; has = true; }  // counter diag
    // NaN or a == float(pi/2): no section -> contributes 0 (matches reference)

    float lossv = 0.0f;
    if (has) {
        float pc = pred[py * WW + px];
        float resp = __expf(0.0f); // placeholder removed below
        resp = expf(pc * 10.0f);
        #pragma unroll
        for (int t = 1; t <= 2; ++t) {
            int y1 = py + t * sy, x1 = px + t * sx;
            int y2 = py - t * sy, x2 = px - t * sx;
            if (y1 >= 0 && y1 < HH && x1 >= 0 && x1 < WW)
                resp += expf(pred[y1 * WW + x1] * 10.0f);
            if (y2 >= 0 && y2 < HH && x2 >= 0 && x2 < WW)
                resp += expf(pred[y2 * WW + x2] * 10.0f);
        }
        lossv = pc * 10.0f - logf(resp + 1e-6f);
    }

    // ---- block reduction (wave = 64) ----
    float v = lossv;
    #pragma unroll
    for (int off = 32; off > 0; off >>= 1) v += __shfl_down(v, off, 64);
    if ((tid & 63) == 0) s_red[tid >> 6] = v;
    __syncthreads();
    if (tid == 0) {
        float s = s_red[0] + s_red[1] + s_red[2] + s_red[3];
        if (use_partials) acc[blockIdx.y * gridDim.x + blockIdx.x] = s;
        else atomicAdd(acc, s);
    }
}

__global__ __launch_bounds__(256) void steal_finalize(const float* __restrict__ acc,
                                                      float* __restrict__ out, int n) {
    __shared__ double sd[256];
    double a = 0.0;
    for (int i = threadIdx.x; i < n; i += 256) a += (double)acc[i];
    sd[threadIdx.x] = a;
    __syncthreads();
    for (int s = 128; s > 0; s >>= 1) {
        if (threadIdx.x < s) sd[threadIdx.x] += sd[threadIdx.x + s];
        __syncthreads();
    }
    if (threadIdx.x == 0) out[0] = (float)(-sd[0] / 4194304.0);
}

extern "C" void kernel_launch(void* const* d_in, const int* in_sizes, int n_in,
                              void* d_out, int out_size, void* d_ws, size_t ws_size,
                              hipStream_t stream) {
    const float* pred = (const float*)d_in[0];   // (1,1,2048,2048) f32
    const float* lab  = (const float*)d_in[1];   // (1,2048,2048) f32
    float* out = (float*)d_out;                  // scalar f32
    float* ws  = (float*)d_ws;

    const int nblocks = (WW / 16) * (HH / 16);   // 16384
    int use_partials = (ws_size >= (size_t)nblocks * sizeof(float)) ? 1 : 0;
    if (!use_partials) hipMemsetAsync(d_ws, 0, sizeof(float), stream);

    dim3 grid(WW / 16, HH / 16), block(16, 16);
    steal_main<<<grid, block, 0, stream>>>(pred, lab, ws, use_partials);
    steal_finalize<<<1, 256, 0, stream>>>(ws, out, use_partials ? nblocks : 1);
}

// Round 2
// 44.085 us; speedup vs baseline: 1.6018x; 1.6018x over previous
//
#include <hip/hip_runtime.h>
#include <math.h>

#define HH 2048
#define WW 2048

// Gaussian sigma=2, 5 taps, normalized (computed in double, rounded to float)
#define GW0 0.15246914402033867f
#define GW1 0.22184129554377693f
#define GW2 0.25137912086578894f

typedef float f4 __attribute__((ext_vector_type(4)));

// LDS layout (floats), with aliasing across dead stages:
//  [0,1760)     : s_lab[40][44]     (later aliased by s_blur[36][37] = 1332)
//  [1760,3240)  : s_h[40][37]       (later aliased by s_gx[34][35] = 1190)
//  [3240,4430)  : s_gy[34][35]
//  [4430,6014)  : s_e[36][44]       exp(pred*10), zero outside image
#define OFF_LAB  0
#define OFF_BLUR 0
#define OFF_H    1760
#define OFF_GX   1760
#define OFF_GY   3240
#define OFF_E    4430
#define SMEM_FLOATS 6014

__global__ __launch_bounds__(256) void steal_main(const float* __restrict__ pred,
                                                  const float* __restrict__ lab,
                                                  float* __restrict__ acc,
                                                  int use_partials) {
    __shared__ float smem[SMEM_FLOATS];
    __shared__ float s_red[4];
    float (*s_lab)[44] = (float(*)[44])(smem + OFF_LAB);
    float (*s_h)[37]   = (float(*)[37])(smem + OFF_H);
    float (*s_blur)[37]= (float(*)[37])(smem + OFF_BLUR);
    float (*s_gx)[35]  = (float(*)[35])(smem + OFF_GX);
    float (*s_gy)[35]  = (float(*)[35])(smem + OFF_GY);
    float (*s_e)[44]   = (float(*)[44])(smem + OFF_E);

    const int tid = threadIdx.x;
    const int tx0 = blockIdx.x * 32, ty0 = blockIdx.y * 32;
    // x-interior: columns tx0-8 .. tx0+35 all in [0, WW) -> vectorizable
    const bool xin = (tx0 >= 32) && (tx0 <= WW - 64);

    if (xin) {
        // labels: 40 rows x 11 float4 (cols tx0-8 .. tx0+35), reflect rows only
        for (int i = tid; i < 40 * 11; i += 256) {
            int r = i / 11, q = i - r * 11;
            int gy = ty0 - 4 + r;
            gy = (gy < 0) ? -gy : ((gy >= HH) ? 2 * HH - 2 - gy : gy);
            f4 v = *(const f4*)(lab + gy * WW + (tx0 - 8) + q * 4);
            *(f4*)(&s_lab[r][q * 4]) = v;
        }
        // exp tile: 36 rows x 11 float4, zero for OOB rows
        for (int i = tid; i < 36 * 11; i += 256) {
            int r = i / 11, q = i - r * 11;
            int gy = ty0 - 2 + r;
            f4 v;
            if (gy >= 0 && gy < HH) {
                f4 p = *(const f4*)(pred + gy * WW + (tx0 - 8) + q * 4);
                v.x = __expf(p.x * 10.0f);
                v.y = __expf(p.y * 10.0f);
                v.z = __expf(p.z * 10.0f);
                v.w = __expf(p.w * 10.0f);
            } else {
                v.x = 0.0f; v.y = 0.0f; v.z = 0.0f; v.w = 0.0f;
            }
            *(f4*)(&s_e[r][q * 4]) = v;
        }
    } else {
        for (int i = tid; i < 40 * 44; i += 256) {
            int r = i / 44, c = i - r * 44;
            int gy = ty0 - 4 + r, gx = tx0 - 8 + c;
            gy = (gy < 0) ? -gy : ((gy >= HH) ? 2 * HH - 2 - gy : gy);
            gx = (gx < 0) ? -gx : ((gx >= WW) ? 2 * WW - 2 - gx : gx);
            s_lab[r][c] = lab[gy * WW + gx];
        }
        for (int i = tid; i < 36 * 44; i += 256) {
            int r = i / 44, c = i - r * 44;
            int gy = ty0 - 2 + r, gx = tx0 - 8 + c;
            float v = 0.0f;
            if (gy >= 0 && gy < HH && gx >= 0 && gx < WW)
                v = __expf(pred[gy * WW + gx] * 10.0f);
            s_e[r][c] = v;
        }
    }
    __syncthreads();

    // ---- horizontal gaussian: 40 rows x 36 out-cols (x coords tx0-2..tx0+33, clamped) ----
    for (int i = tid; i < 40 * 36; i += 256) {
        int r = i / 36, j = i - r * 36;
        int qx = tx0 - 2 + j;
        qx = min(max(qx, 0), WW - 1);
        int b = qx - (tx0 - 8);
        s_h[r][j] = GW0 * (s_lab[r][b - 2] + s_lab[r][b + 2]) +
                    GW1 * (s_lab[r][b - 1] + s_lab[r][b + 1]) +
                    GW2 * s_lab[r][b];
    }
    __syncthreads();

    // ---- vertical gaussian -> blur(clampY, clampX), 36x36 (aliases lab) ----
    for (int i = tid; i < 36 * 36; i += 256) {
        int r = i / 36, j = i - r * 36;
        int qy = ty0 - 2 + r;
        qy = min(max(qy, 0), HH - 1);
        int b = qy - (ty0 - 4);
        s_blur[r][j] = GW0 * (s_h[b - 2][j] + s_h[b + 2][j]) +
                       GW1 * (s_h[b - 1][j] + s_h[b + 1][j]) +
                       GW2 * s_h[b][j];
    }
    __syncthreads();

    // ---- first sobel (replicate pad): 34x34, gx aliases h ----
    for (int i = tid; i < 34 * 34; i += 256) {
        int r = i / 34, j = i - r * 34;
        int qy = ty0 - 1 + r;  qy = min(max(qy, 0), HH - 1);
        int qx = tx0 - 1 + j;  qx = min(max(qx, 0), WW - 1);
        int br = qy - (ty0 - 2), bc = qx - (tx0 - 2);
        float m11 = s_blur[br - 1][bc - 1], m12 = s_blur[br - 1][bc], m13 = s_blur[br - 1][bc + 1];
        float m21 = s_blur[br][bc - 1],                               m23 = s_blur[br][bc + 1];
        float m31 = s_blur[br + 1][bc - 1], m32 = s_blur[br + 1][bc], m33 = s_blur[br + 1][bc + 1];
        s_gx[r][j] = ((m13 - m11) + 2.0f * (m23 - m21) + (m33 - m31)) * 0.125f;
        s_gy[r][j] = ((m31 - m11) + 2.0f * (m32 - m12) + (m33 - m13)) * 0.125f;
    }
    __syncthreads();

    // ---- per pixel: second sobel, section via tan-domain compares, directional loss ----
    const int lcol = tid & 31, lrow0 = tid >> 5;
    const float T1 = 0.41421356237309503f;  // tan(pi/8)
    const float T3 = 2.41421356237309510f;  // tan(3pi/8)
    float lsum = 0.0f;

    #pragma unroll
    for (int k = 0; k < 4; ++k) {
        const int lr = lrow0 + 8 * k;
        const int gr = lr + 1, gc = lcol + 1;  // slot in 34x34 tiles

        float a11 = s_gx[gr - 1][gc - 1], a13 = s_gx[gr - 1][gc + 1];
        float a21 = s_gx[gr][gc - 1],     a23 = s_gx[gr][gc + 1];
        float a31 = s_gx[gr + 1][gc - 1], a33 = s_gx[gr + 1][gc + 1];
        float b11 = s_gy[gr - 1][gc - 1], b12 = s_gy[gr - 1][gc], b13 = s_gy[gr - 1][gc + 1];
        float b21 = s_gy[gr][gc - 1],                             b23 = s_gy[gr][gc + 1];
        float b31 = s_gy[gr + 1][gc - 1], b32 = s_gy[gr + 1][gc], b33 = s_gy[gr + 1][gc + 1];

        float gxx = ((a13 - a11) + 2.0f * (a23 - a21) + (a33 - a31)) * 0.125f;
        float gxy = ((b13 - b11) + 2.0f * (b23 - b21) + (b33 - b31)) * 0.125f;
        float gyy = ((b31 - b11) + 2.0f * (b32 - b12) + (b33 - b13)) * 0.125f;

        float sg = -(gxy + 1e-6f);
        float sgn = (sg > 0.0f) ? 1.0f : ((sg < 0.0f) ? -1.0f : 0.0f);
        float ratio = gyy * sgn / (gxx + 1e-6f);

        int sy, sx; bool has = true;
        if (ratio >= -T1 && ratio < T1)        { sy = 0; sx = 1;  }  // horiz
        else if (ratio >= T1 && ratio < T3)    { sy = 1; sx = 1;  }  // lead diag
        else if (ratio >= -T3 && ratio < -T1)  { sy = 1; sx = -1; }  // counter diag
        else if (ratio >= T3 || ratio < -T3)   { sy = 1; sx = 0;  }  // vert
        else                                   { sy = 0; sx = 0; has = false; }  // NaN

        const float* ep = smem + OFF_E;
        int base = (lr + 2) * 44 + (lcol + 8);
        int step = sy * 44 + sx;
        float resp = ep[base - 2 * step] + ep[base - step] + ep[base] +
                     ep[base + step] + ep[base + 2 * step];

        float pc = pred[(ty0 + lr) * WW + (tx0 + lcol)];
        float lv = pc * 10.0f - __logf(resp + 1e-6f);
        lsum += has ? lv : 0.0f;
    }

    // ---- block reduction (wave = 64) ----
    float v = lsum;
    #pragma unroll
    for (int off = 32; off > 0; off >>= 1) v += __shfl_down(v, off, 64);
    if ((tid & 63) == 0) s_red[tid >> 6] = v;
    __syncthreads();
    if (tid == 0) {
        float s = s_red[0] + s_red[1] + s_red[2] + s_red[3];
        if (use_partials) acc[blockIdx.y * gridDim.x + blockIdx.x] = s;
        else atomicAdd(acc, s);
    }
}

__global__ __launch_bounds__(256) void steal_finalize(const float* __restrict__ acc,
                                                      float* __restrict__ out, int n) {
    __shared__ double sd[256];
    double a = 0.0;
    for (int i = threadIdx.x; i < n; i += 256) a += (double)acc[i];
    sd[threadIdx.x] = a;
    __syncthreads();
    for (int s = 128; s > 0; s >>= 1) {
        if (threadIdx.x < s) sd[threadIdx.x] += sd[threadIdx.x + s];
        __syncthreads();
    }
    if (threadIdx.x == 0) out[0] = (float)(-sd[0] / 4194304.0);
}

extern "C" void kernel_launch(void* const* d_in, const int* in_sizes, int n_in,
                              void* d_out, int out_size, void* d_ws, size_t ws_size,
                              hipStream_t stream) {
    const float* pred = (const float*)d_in[0];   // (1,1,2048,2048) f32
    const float* lab  = (const float*)d_in[1];   // (1,2048,2048) f32
    float* out = (float*)d_out;                  // scalar f32
    float* ws  = (float*)d_ws;

    const int gx = WW / 32, gy = HH / 32;        // 64 x 64 = 4096 blocks
    const int nblocks = gx * gy;
    int use_partials = (ws_size >= (size_t)nblocks * sizeof(float)) ? 1 : 0;
    if (!use_partials) hipMemsetAsync(d_ws, 0, sizeof(float), stream);

    dim3 grid(gx, gy), block(256);
    steal_main<<<grid, block, 0, stream>>>(pred, lab, ws, use_partials);
    steal_finalize<<<1, 256, 0, stream>>>(ws, out, use_partials ? nblocks : 1);
}

// Round 3
// 40.545 us; speedup vs baseline: 1.7416x; 1.0873x over previous
//
#include <hip/hip_runtime.h>
#include <math.h>

#define HH 2048
#define WW 2048
#define STR 44

// Gaussian sigma=2, 5 taps, normalized
#define GW0 0.15246914402033867f
#define GW1 0.22184129554377693f
#define GW2 0.25137912086578894f

typedef float f4 __attribute__((ext_vector_type(4)));

// LDS float offsets (all tiles stride 44, 16B-aligned bases):
//  lab  : 40 rows, slots [0,40) = x in [-4,36)      (aliased later by blur: 36 rows, slot=x+2)
//  h    : 40 rows, slots [0,36) = x in [-2,34)      (aliased later by gx: 34 rows, slot=x+1)
//  gy   : 34 rows, slots [0,34)
//  e    : 36 rows (y in [-2,34)), slots [0,40) = x in [-4,36), exp(pred*10), 0 outside image
#define OFF_LAB  0
#define OFF_H    1760
#define OFF_GY   3520
#define OFF_E    5016
#define SMEM_FLOATS 6600

__global__ __launch_bounds__(256) void steal_main(const float* __restrict__ pred,
                                                  const float* __restrict__ lab,
                                                  float* __restrict__ acc,
                                                  int use_partials) {
    __shared__ float sm[SMEM_FLOATS];
    __shared__ float s_red[4];
    float* lab_t  = sm + OFF_LAB;
    float* blur_t = sm + OFF_LAB;   // alias (lab dead after h-pass)
    float* h_t    = sm + OFF_H;
    float* gx_t   = sm + OFF_H;     // alias (h dead after v-pass)
    float* gy_t   = sm + OFF_GY;
    float* e_t    = sm + OFF_E;

    const int tid = threadIdx.x;
    const int tx0 = blockIdx.x * 32, ty0 = blockIdx.y * 32;
    const bool xin = (tx0 >= 32) && (tx0 <= WW - 64);
    const bool yin = (ty0 >= 32) && (ty0 <= HH - 64);

    // ---------------- fill: lab (reflect) + e = exp(pred*10) (zero pad) ----------------
    if (xin) {
        for (int i = tid; i < 400; i += 256) {           // 40 rows x 10 f4
            int r = i / 10, q = i - r * 10;
            int gy = ty0 - 4 + r;
            gy = (gy < 0) ? -gy : ((gy >= HH) ? 2 * HH - 2 - gy : gy);
            *(f4*)(lab_t + r * STR + q * 4) = *(const f4*)(lab + gy * WW + (tx0 - 4) + q * 4);
        }
        for (int i = tid; i < 360; i += 256) {           // 36 rows x 10 f4
            int r = i / 10, q = i - r * 10;
            int gy = ty0 - 2 + r;
            f4 v = {0.0f, 0.0f, 0.0f, 0.0f};
            if (gy >= 0 && gy < HH) {
                f4 p = *(const f4*)(pred + gy * WW + (tx0 - 4) + q * 4);
                v.x = __expf(p.x * 10.0f); v.y = __expf(p.y * 10.0f);
                v.z = __expf(p.z * 10.0f); v.w = __expf(p.w * 10.0f);
            }
            *(f4*)(e_t + r * STR + q * 4) = v;
        }
    } else {
        for (int i = tid; i < 1600; i += 256) {          // 40 x 40 scalar, reflect both dims
            int r = i / 40, c = i - r * 40;
            int gy = ty0 - 4 + r, gx = tx0 - 4 + c;
            gy = (gy < 0) ? -gy : ((gy >= HH) ? 2 * HH - 2 - gy : gy);
            gx = (gx < 0) ? -gx : ((gx >= WW) ? 2 * WW - 2 - gx : gx);
            lab_t[r * STR + c] = lab[gy * WW + gx];
        }
        for (int i = tid; i < 1440; i += 256) {          // 36 x 40 scalar, zero pad
            int r = i / 40, c = i - r * 40;
            int gy = ty0 - 2 + r, gx = tx0 - 4 + c;
            float v = 0.0f;
            if (gy >= 0 && gy < HH && gx >= 0 && gx < WW)
                v = __expf(pred[gy * WW + gx] * 10.0f);
            e_t[r * STR + c] = v;
        }
    }
    __syncthreads();

    // ---------------- horizontal gaussian: h slot s = x+2, 40 rows x 36 cols ----------------
    if (xin) {
        for (int i = tid; i < 360; i += 256) {           // 40 rows x 9 chunks
            int r = i / 9, j = i - r * 9;
            const float* lr_ = lab_t + r * STR + j * 4;
            f4 a = *(const f4*)(lr_);
            f4 b = *(const f4*)(lr_ + 4);
            f4 o;
            o.x = GW0 * (a.x + b.x) + GW1 * (a.y + a.w) + GW2 * a.z;
            o.y = GW0 * (a.y + b.y) + GW1 * (a.z + b.x) + GW2 * a.w;
            o.z = GW0 * (a.z + b.z) + GW1 * (a.w + b.y) + GW2 * b.x;
            o.w = GW0 * (a.w + b.w) + GW1 * (b.x + b.z) + GW2 * b.y;
            *(f4*)(h_t + r * STR + j * 4) = o;
        }
    } else {
        for (int i = tid; i < 1440; i += 256) {          // 40 x 36 scalar with x clamp
            int r = i / 36, j = i - r * 36;
            int qx = tx0 - 2 + j;
            qx = min(max(qx, 0), WW - 1);
            int b = qx - (tx0 - 4);
            h_t[r * STR + j] = GW0 * (lab_t[r * STR + b - 2] + lab_t[r * STR + b + 2]) +
                               GW1 * (lab_t[r * STR + b - 1] + lab_t[r * STR + b + 1]) +
                               GW2 * lab_t[r * STR + b];
        }
    }
    __syncthreads();

    // ---------------- vertical gaussian -> blur (aliases lab), slot = x+2, 36x36 ----------------
    if (yin) {
        for (int i = tid; i < 324; i += 256) {           // 36 rows x 9 chunks
            int r = i / 9, j = i - r * 9;
            const float* hc = h_t + r * STR + j * 4;
            f4 v0 = *(const f4*)(hc);
            f4 v1 = *(const f4*)(hc + STR);
            f4 v2 = *(const f4*)(hc + 2 * STR);
            f4 v3 = *(const f4*)(hc + 3 * STR);
            f4 v4 = *(const f4*)(hc + 4 * STR);
            f4 o = GW0 * (v0 + v4) + GW1 * (v1 + v3) + GW2 * v2;
            *(f4*)(blur_t + r * STR + j * 4) = o;
        }
    } else {
        for (int i = tid; i < 1296; i += 256) {          // 36 x 36 scalar with y clamp
            int r = i / 36, j = i - r * 36;
            int qy = ty0 - 2 + r;
            qy = min(max(qy, 0), HH - 1);
            int b = qy - (ty0 - 4);
            blur_t[r * STR + j] = GW0 * (h_t[(b - 2) * STR + j] + h_t[(b + 2) * STR + j]) +
                                  GW1 * (h_t[(b - 1) * STR + j] + h_t[(b + 1) * STR + j]) +
                                  GW2 * h_t[b * STR + j];
        }
    }
    __syncthreads();

    // ---------------- first sobel (replicate): gx (aliases h), gy; slot = x+1, 34x34 ----------------
    if (xin && yin) {
        for (int i = tid; i < 306; i += 256) {           // 34 rows x 9 chunks
            int r = i / 9, j = i - r * 9;
            const float* bc = blur_t + r * STR + j * 4;
            f4 r0a = *(const f4*)(bc),            r0b = *(const f4*)(bc + 4);
            f4 r1a = *(const f4*)(bc + STR),      r1b = *(const f4*)(bc + STR + 4);
            f4 r2a = *(const f4*)(bc + 2 * STR),  r2b = *(const f4*)(bc + 2 * STR + 4);
            float w0[8] = {r0a.x, r0a.y, r0a.z, r0a.w, r0b.x, r0b.y, r0b.z, r0b.w};
            float w1[8] = {r1a.x, r1a.y, r1a.z, r1a.w, r1b.x, r1b.y, r1b.z, r1b.w};
            float w2[8] = {r2a.x, r2a.y, r2a.z, r2a.w, r2b.x, r2b.y, r2b.z, r2b.w};
            float ox[4], oy[4];
            #pragma unroll
            for (int k = 0; k < 4; ++k) {
                float t11 = w0[k], t12 = w0[k + 1], t13 = w0[k + 2];
                float t21 = w1[k],                  t23 = w1[k + 2];
                float t31 = w2[k], t32 = w2[k + 1], t33 = w2[k + 2];
                ox[k] = ((t13 - t11) + 2.0f * (t23 - t21) + (t33 - t31)) * 0.125f;
                oy[k] = ((t31 - t11) + 2.0f * (t32 - t12) + (t33 - t13)) * 0.125f;
            }
            f4 vgx = {ox[0], ox[1], ox[2], ox[3]};
            f4 vgy = {oy[0], oy[1], oy[2], oy[3]};
            *(f4*)(gx_t + r * STR + j * 4) = vgx;
            *(f4*)(gy_t + r * STR + j * 4) = vgy;
        }
    } else {
        for (int i = tid; i < 1156; i += 256) {          // 34 x 34 scalar with clamps
            int r = i / 34, j = i - r * 34;
            int qy = ty0 - 1 + r;  qy = min(max(qy, 0), HH - 1);
            int qx = tx0 - 1 + j;  qx = min(max(qx, 0), WW - 1);
            int br = qy - (ty0 - 2), bc2 = qx - (tx0 - 2);
            const float* b0 = blur_t + (br - 1) * STR + bc2;
            const float* b1 = blur_t + br * STR + bc2;
            const float* b2 = blur_t + (br + 1) * STR + bc2;
            float m11 = b0[-1], m12 = b0[0], m13 = b0[1];
            float m21 = b1[-1],              m23 = b1[1];
            float m31 = b2[-1], m32 = b2[0], m33 = b2[1];
            gx_t[r * STR + j] = ((m13 - m11) + 2.0f * (m23 - m21) + (m33 - m31)) * 0.125f;
            gy_t[r * STR + j] = ((m31 - m11) + 2.0f * (m32 - m12) + (m33 - m13)) * 0.125f;
        }
    }
    __syncthreads();

    // ---------------- per-pixel: second sobel, section, directional loss (vector, all blocks) ----
    const int pyr = tid >> 3;          // pixel row 0..31
    const int x0 = (tid & 7) * 4;      // pixel col chunk base
    const float T1 = 0.41421356237309503f;   // tan(pi/8)
    const float T3 = 2.41421356237309510f;   // tan(3pi/8)

    float ratio[4];
    {
        const float* gxb = gx_t + pyr * STR + x0;
        const float* gyb = gy_t + pyr * STR + x0;
        f4 x0a = *(const f4*)(gxb),            x0b = *(const f4*)(gxb + 4);
        f4 x1a = *(const f4*)(gxb + STR),      x1b = *(const f4*)(gxb + STR + 4);
        f4 x2a = *(const f4*)(gxb + 2 * STR),  x2b = *(const f4*)(gxb + 2 * STR + 4);
        f4 y0a = *(const f4*)(gyb),            y0b = *(const f4*)(gyb + 4);
        f4 y1a = *(const f4*)(gyb + STR),      y1b = *(const f4*)(gyb + STR + 4);
        f4 y2a = *(const f4*)(gyb + 2 * STR),  y2b = *(const f4*)(gyb + 2 * STR + 4);
        float ax0[8] = {x0a.x, x0a.y, x0a.z, x0a.w, x0b.x, x0b.y, x0b.z, x0b.w};
        float ax1[8] = {x1a.x, x1a.y, x1a.z, x1a.w, x1b.x, x1b.y, x1b.z, x1b.w};
        float ax2[8] = {x2a.x, x2a.y, x2a.z, x2a.w, x2b.x, x2b.y, x2b.z, x2b.w};
        float ay0[8] = {y0a.x, y0a.y, y0a.z, y0a.w, y0b.x, y0b.y, y0b.z, y0b.w};
        float ay1[8] = {y1a.x, y1a.y, y1a.z, y1a.w, y1b.x, y1b.y, y1b.z, y1b.w};
        float ay2[8] = {y2a.x, y2a.y, y2a.z, y2a.w, y2b.x, y2b.y, y2b.z, y2b.w};
        #pragma unroll
        for (int k = 0; k < 4; ++k) {
            float gxx = ((ax0[k + 2] - ax0[k]) + 2.0f * (ax1[k + 2] - ax1[k]) +
                         (ax2[k + 2] - ax2[k])) * 0.125f;
            float gxy = ((ay0[k + 2] - ay0[k]) + 2.0f * (ay1[k + 2] - ay1[k]) +
                         (ay2[k + 2] - ay2[k])) * 0.125f;
            float gyy = ((ay2[k] - ay0[k]) + 2.0f * (ay2[k + 1] - ay0[k + 1]) +
                         (ay2[k + 2] - ay0[k + 2])) * 0.125f;
            float sg = -(gxy + 1e-6f);
            float sgn = (sg > 0.0f) ? 1.0f : ((sg < 0.0f) ? -1.0f : 0.0f);
            ratio[k] = gyy * sgn * __builtin_amdgcn_rcpf(gxx + 1e-6f);
        }
    }

    float hsum[4], vsum[4], dl[4], dc[4];
    #pragma unroll
    for (int k = 0; k < 4; ++k) { vsum[k] = 0.0f; dl[k] = 0.0f; dc[k] = 0.0f; hsum[k] = 0.0f; }
    #pragma unroll
    for (int t = 0; t < 5; ++t) {
        const float* er = e_t + (pyr + t) * STR + x0;
        f4 ea = *(const f4*)(er), eb = *(const f4*)(er + 4), ec = *(const f4*)(er + 8);
        float w[12] = {ea.x, ea.y, ea.z, ea.w, eb.x, eb.y, eb.z, eb.w, ec.x, ec.y, ec.z, ec.w};
        #pragma unroll
        for (int k = 0; k < 4; ++k) {
            int m = k + 4;
            vsum[k] += w[m];
            dl[k] += w[m + t - 2];
            dc[k] += w[m - t + 2];
        }
        if (t == 2) {
            #pragma unroll
            for (int k = 0; k < 4; ++k) {
                int m = k + 4;
                hsum[k] = w[m - 2] + w[m - 1] + w[m] + w[m + 1] + w[m + 2];
            }
        }
    }

    f4 pc = *(const f4*)(pred + (ty0 + pyr) * WW + tx0 + x0);
    float pcv[4] = {pc.x, pc.y, pc.z, pc.w};
    float lsum = 0.0f;
    #pragma unroll
    for (int k = 0; k < 4; ++k) {
        float rt = ratio[k];
        bool isH = (rt >= -T1) && (rt < T1);
        bool isL = (rt >= T1) && (rt < T3);
        bool isC = (rt >= -T3) && (rt < -T1);
        bool has = isH || isL || isC || (rt >= T3) || (rt < -T3);   // false only for NaN
        float resp = isH ? hsum[k] : (isL ? dl[k] : (isC ? dc[k] : vsum[k]));
        float lv = pcv[k] * 10.0f - __logf(resp + 1e-6f);
        lsum += has ? lv : 0.0f;
    }

    // ---------------- block reduction (wave = 64) ----------------
    float v = lsum;
    #pragma unroll
    for (int off = 32; off > 0; off >>= 1) v += __shfl_down(v, off, 64);
    if ((tid & 63) == 0) s_red[tid >> 6] = v;
    __syncthreads();
    if (tid == 0) {
        float s = s_red[0] + s_red[1] + s_red[2] + s_red[3];
        if (use_partials) acc[blockIdx.y * gridDim.x + blockIdx.x] = s;
        else atomicAdd(acc, s);
    }
}

__global__ __launch_bounds__(256) void steal_finalize(const float* __restrict__ acc,
                                                      float* __restrict__ out, int n) {
    __shared__ double sd[256];
    double a = 0.0;
    int n4 = n >> 2;
    for (int i = threadIdx.x; i < n4; i += 256) {
        f4 v = *(const f4*)(acc + i * 4);
        a += (double)v.x + (double)v.y + (double)v.z + (double)v.w;
    }
    for (int i = (n4 << 2) + threadIdx.x; i < n; i += 256) a += (double)acc[i];
    sd[threadIdx.x] = a;
    __syncthreads();
    for (int s = 128; s > 0; s >>= 1) {
        if (threadIdx.x < s) sd[threadIdx.x] += sd[threadIdx.x + s];
        __syncthreads();
    }
    if (threadIdx.x == 0) out[0] = (float)(-sd[0] / 4194304.0);
}

extern "C" void kernel_launch(void* const* d_in, const int* in_sizes, int n_in,
                              void* d_out, int out_size, void* d_ws, size_t ws_size,
                              hipStream_t stream) {
    const float* pred = (const float*)d_in[0];   // (1,1,2048,2048) f32
    const float* lab  = (const float*)d_in[1];   // (1,2048,2048) f32
    float* out = (float*)d_out;                  // scalar f32
    float* ws  = (float*)d_ws;

    const int gx = WW / 32, gy = HH / 32;        // 64 x 64 = 4096 blocks
    const int nblocks = gx * gy;
    int use_partials = (ws_size >= (size_t)nblocks * sizeof(float)) ? 1 : 0;
    if (!use_partials) hipMemsetAsync(d_ws, 0, sizeof(float), stream);

    dim3 grid(gx, gy), block(256);
    steal_main<<<grid, block, 0, stream>>>(pred, lab, ws, use_partials);
    steal_finalize<<<1, 256, 0, stream>>>(ws, out, use_partials ? nblocks : 1);
}

// Round 4
// 36.287 us; speedup vs baseline: 1.9460x; 1.1173x over previous
//
#include <hip/hip_runtime.h>
#include <math.h>

#define HH 2048
#define WW 2048
#define T 8

// Gaussian sigma=2, 5 taps, normalized
#define GW0 0.15246914402033867f
#define GW1 0.22184129554377693f
#define GW2 0.25137912086578894f

typedef float f4 __attribute__((ext_vector_type(4)));

struct R8 { float v[8]; };
struct R6 { float v[6]; };

// Load lab virtual row vr (vertical reflect), return h row covering x = xb-2 .. xb+5.
// Horizontal reflect handled in-register on edge lanes (le: lane0 of strip 0, re: lane63 of strip 7).
__device__ __forceinline__ R8 hrow(const float* __restrict__ lab, int vr, int xb,
                                   bool edgew, bool le, bool re) {
    int r = vr < 0 ? -vr : (vr >= HH ? 2 * HH - 2 - vr : vr);
    const float* row = lab + (size_t)r * WW;
    f4 A = *(const f4*)(row + max(xb - 4, 0));
    f4 B = *(const f4*)(row + xb);
    f4 C = *(const f4*)(row + min(xb + 4, WW - 4));
    float w[12] = {A.x, A.y, A.z, A.w, B.x, B.y, B.z, B.w, C.x, C.y, C.z, C.w};
    if (edgew) {
        if (le) { w[0] = C.x; w[1] = B.w; w[2] = B.z; w[3] = B.y; }          // lab[-4..-1]=lab[4,3,2,1]
        if (re) { w[8] = B.z; w[9] = B.y; w[10] = B.x; w[11] = A.w; }        // lab[2048..2051]=lab[2046..2043]
    }
    R8 h;
    #pragma unroll
    for (int j = 0; j < 8; ++j)
        h.v[j] = GW0 * (w[j] + w[j + 4]) + GW1 * (w[j + 1] + w[j + 3]) + GW2 * w[j + 2];
    return h;
}

// Vertical gaussian; output blur row covering x = xb-2 .. xb+5, with x-clamp fixups for sobel use.
__device__ __forceinline__ R8 vg(const R8& a, const R8& b, const R8& c, const R8& d, const R8& e_,
                                 bool edgew, bool le, bool re) {
    R8 o;
    #pragma unroll
    for (int j = 0; j < 8; ++j)
        o.v[j] = GW0 * (a.v[j] + e_.v[j]) + GW1 * (b.v[j] + d.v[j]) + GW2 * c.v[j];
    if (edgew) {
        if (le) { o.v[0] = o.v[2]; o.v[1] = o.v[2]; }   // blur[-2],[-1] -> blur[0]
        if (re) { o.v[6] = o.v[5]; o.v[7] = o.v[5]; }   // blur[2048],[2049] -> blur[2047]
    }
    return o;
}

// First sobel: inputs 8-wide blur rows (up/mid/dn), outputs 6-wide gx,gy covering x = xb-1 .. xb+4,
// with x-clamp dup on edges for the second sobel.
__device__ __forceinline__ void sobel(const R8& u, const R8& m, const R8& d, R6& ox, R6& oy,
                                      bool edgew, bool le, bool re) {
    #pragma unroll
    for (int j = 0; j < 6; ++j) {
        ox.v[j] = ((u.v[j+2] - u.v[j]) + 2.f*(m.v[j+2] - m.v[j]) + (d.v[j+2] - d.v[j])) * 0.125f;
        oy.v[j] = ((d.v[j] - u.v[j]) + 2.f*(d.v[j+1] - u.v[j+1]) + (d.v[j+2] - u.v[j+2])) * 0.125f;
    }
    if (edgew) {
        if (le) { ox.v[0] = ox.v[1]; oy.v[0] = oy.v[1]; }   // gx[-1] -> gx[0]
        if (re) { ox.v[5] = ox.v[4]; oy.v[5] = oy.v[4]; }   // gx[2048] -> gx[2047]
    }
}

// e = exp(pred*10) row ry, 8-wide covering x = xb-2 .. xb+5, zero outside image.
__device__ __forceinline__ R8 erow(const float* __restrict__ pred, int ry, int xb,
                                   bool edgew, bool le, bool re) {
    R8 o;
    if (ry < 0 || ry >= HH) {           // wave-uniform
        #pragma unroll
        for (int j = 0; j < 8; ++j) o.v[j] = 0.f;
        return o;
    }
    const float* row = pred + (size_t)ry * WW;
    f4 A = *(const f4*)(row + max(xb - 4, 0));
    f4 B = *(const f4*)(row + xb);
    f4 C = *(const f4*)(row + min(xb + 4, WW - 4));
    float w[8] = {A.z, A.w, B.x, B.y, B.z, B.w, C.x, C.y};
    #pragma unroll
    for (int j = 0; j < 8; ++j) o.v[j] = __expf(w[j] * 10.f);
    if (edgew) {
        if (le) { o.v[0] = 0.f; o.v[1] = 0.f; }
        if (re) { o.v[6] = 0.f; o.v[7] = 0.f; }
    }
    return o;
}

__global__ __launch_bounds__(256, 2) void steal_main(const float* __restrict__ pred,
                                                     const float* __restrict__ lab,
                                                     float* __restrict__ acc) {
    const int lane = threadIdx.x & 63;
    const int wid  = (blockIdx.x << 2) + (threadIdx.x >> 6);   // 0..2047
    const int sx = wid & 7;
    const int y0 = (wid >> 3) * T;
    const int xb = sx * 256 + lane * 4;
    const bool edgew = (sx == 0) || (sx == 7);                 // wave-uniform
    const bool le = (sx == 0) && (lane == 0);
    const bool re = (sx == 7) && (lane == 63);

    const float T1f = 0.41421356237309503f;   // tan(pi/8)
    const float T3f = 2.41421356237309510f;   // tan(3pi/8)

    // ---------------- prime ----------------
    R8 A0 = hrow(lab, y0-4, xb, edgew, le, re);
    R8 A1 = hrow(lab, y0-3, xb, edgew, le, re);
    R8 A2 = hrow(lab, y0-2, xb, edgew, le, re);
    R8 A3 = hrow(lab, y0-1, xb, edgew, le, re);
    R8 H0 = hrow(lab, y0+0, xb, edgew, le, re);
    R8 H1 = hrow(lab, y0+1, xb, edgew, le, re);
    R8 H2 = hrow(lab, y0+2, xb, edgew, le, re);
    R8 H3 = hrow(lab, y0+3, xb, edgew, le, re);
    R8 bm2 = vg(A0, A1, A2, A3, H0, edgew, le, re);   // blur[y0-2]
    R8 bm1 = vg(A1, A2, A3, H0, H1, edgew, le, re);   // blur[y0-1]
    R8 b0  = vg(A2, A3, H0, H1, H2, edgew, le, re);   // blur[y0]
    R8 b1  = vg(A3, H0, H1, H2, H3, edgew, le, re);   // blur[y0+1]
    R6 gx0, gy0, gx1, gy1;
    if (y0 > 0) {
        sobel(bm2, bm1, b0, gx0, gy0, edgew, le, re); // gxgy[y0-1]
        sobel(bm1, b0,  b1, gx1, gy1, edgew, le, re); // gxgy[y0]
    } else {
        sobel(b0, b0, b1, gx1, gy1, edgew, le, re);   // gxgy[0] (y-clamp dup of blur[-1])
        gx0 = gx1; gy0 = gy1;                          // gxgy[-1] -> gxgy[0]
    }
    R8 e0 = erow(pred, y0-2, xb, edgew, le, re);
    R8 e1 = erow(pred, y0-1, xb, edgew, le, re);
    R8 e2 = erow(pred, y0+0, xb, edgew, le, re);
    R8 e3 = erow(pred, y0+1, xb, edgew, le, re);

    float lsum = 0.f;

    // ---------------- main loop: 8 output rows ----------------
    for (int i = 0; i < T; ++i) {
        const int y = y0 + i;

        R8 bn;                                          // blur[y+2]
        if (y + 2 < HH) {
            R8 hn = hrow(lab, y + 4, xb, edgew, le, re);
            bn = vg(H0, H1, H2, H3, hn, edgew, le, re);
            H0 = H1; H1 = H2; H2 = H3; H3 = hn;
        } else bn = b1;                                 // dup blur[H-1]

        R6 gxn, gyn;                                    // gxgy[y+1]
        if (y + 1 < HH) sobel(b0, b1, bn, gxn, gyn, edgew, le, re);
        else { gxn = gx1; gyn = gy1; }                  // dup gxgy[H-1]

        R8 en = erow(pred, y + 2, xb, edgew, le, re);   // e[y+2]

        f4 pc4 = *(const f4*)(pred + (size_t)y * WW + xb);
        float pcv[4] = {pc4.x, pc4.y, pc4.z, pc4.w};

        #pragma unroll
        for (int k = 0; k < 4; ++k) {
            float gxx = ((gx0.v[k+2]-gx0.v[k]) + 2.f*(gx1.v[k+2]-gx1.v[k]) +
                         (gxn.v[k+2]-gxn.v[k])) * 0.125f;
            float gxy = ((gy0.v[k+2]-gy0.v[k]) + 2.f*(gy1.v[k+2]-gy1.v[k]) +
                         (gyn.v[k+2]-gyn.v[k])) * 0.125f;
            float gyy = ((gyn.v[k]-gy0.v[k]) + 2.f*(gyn.v[k+1]-gy0.v[k+1]) +
                         (gyn.v[k+2]-gy0.v[k+2])) * 0.125f;
            float sg = -(gxy + 1e-6f);
            float sgn = (sg > 0.f) ? 1.f : ((sg < 0.f) ? -1.f : 0.f);
            float rt = gyy * sgn * __builtin_amdgcn_rcpf(gxx + 1e-6f);

            float hs  = e2.v[k] + e2.v[k+1] + e2.v[k+2] + e2.v[k+3] + e2.v[k+4];
            float vs  = e0.v[k+2] + e1.v[k+2] + e2.v[k+2] + e3.v[k+2] + en.v[k+2];
            float dls = e0.v[k]   + e1.v[k+1] + e2.v[k+2] + e3.v[k+3] + en.v[k+4];
            float dcs = e0.v[k+4] + e1.v[k+3] + e2.v[k+2] + e3.v[k+1] + en.v[k];

            bool isH = (rt >= -T1f) && (rt < T1f);
            bool isL = (rt >=  T1f) && (rt < T3f);
            bool isC = (rt >= -T3f) && (rt < -T1f);
            bool has = isH || isL || isC || (rt >= T3f) || (rt < -T3f);  // false only for NaN
            float resp = isH ? hs : (isL ? dls : (isC ? dcs : vs));
            float lv = pcv[k] * 10.f - __logf(resp + 1e-6f);
            lsum += has ? lv : 0.f;
        }

        // rotate windows
        b0 = b1; b1 = bn;
        gx0 = gx1; gx1 = gxn; gy0 = gy1; gy1 = gyn;
        e0 = e1; e1 = e2; e2 = e3; e3 = en;
    }

    // ---------------- wave reduction ----------------
    #pragma unroll
    for (int off = 32; off; off >>= 1) lsum += __shfl_down(lsum, off, 64);
    if (lane == 0) acc[wid] = lsum;
}

__global__ __launch_bounds__(256) void steal_finalize(const float* __restrict__ acc,
                                                      float* __restrict__ out, int n) {
    __shared__ double sd[256];
    double a = 0.0;
    int n4 = n >> 2;
    for (int i = threadIdx.x; i < n4; i += 256) {
        f4 v = *(const f4*)(acc + i * 4);
        a += (double)v.x + (double)v.y + (double)v.z + (double)v.w;
    }
    for (int i = (n4 << 2) + threadIdx.x; i < n; i += 256) a += (double)acc[i];
    sd[threadIdx.x] = a;
    __syncthreads();
    for (int s = 128; s > 0; s >>= 1) {
        if (threadIdx.x < s) sd[threadIdx.x] += sd[threadIdx.x + s];
        __syncthreads();
    }
    if (threadIdx.x == 0) out[0] = (float)(-sd[0] / 4194304.0);
}

extern "C" void kernel_launch(void* const* d_in, const int* in_sizes, int n_in,
                              void* d_out, int out_size, void* d_ws, size_t ws_size,
                              hipStream_t stream) {
    const float* pred = (const float*)d_in[0];   // (1,1,2048,2048) f32
    const float* lab  = (const float*)d_in[1];   // (1,2048,2048) f32
    float* out = (float*)d_out;                  // scalar f32
    float* ws  = (float*)d_ws;

    const int nwaves = 8 * (HH / T);             // 2048 wave-jobs
    const int nblocks = nwaves / 4;              // 512 blocks x 256 threads

    steal_main<<<nblocks, 256, 0, stream>>>(pred, lab, ws);
    steal_finalize<<<1, 256, 0, stream>>>(ws, out, nwaves);
}